// Round 8
// baseline (913.060 us; speedup 1.0000x reference)
//
#include <hip/hip_runtime.h>
#include <hip/hip_fp16.h>
#include <math.h>

#define NHEAD 8
#define NEG_SLOPE 0.2f
#define OUT_COLS 80

__device__ __forceinline__ float lrelu(float x) {
    return x > 0.f ? x : NEG_SLOPE * x;
}

// ---------------- projection: outer-product tile + LDS x-staging ----------------
// Block = 4 waves / 256 thr, covers 128 nodes x 128 cols (wave = 32-col chunk).
// All 4 waves consume the SAME x rows -> stage each 32-k chunk in LDS once
// (coalesced float4), [k][node] layout (2-way bank alias = free), double-buffered.
template<int HC, int C>
__device__ __forceinline__ void proj_epilogue(
    const float (&acc)[32], int n, int n_nodes, int j0, int j0u,
    const float* __restrict__ as_flat, const float* __restrict__ ad_flat,
    __half* __restrict__ xp, float* __restrict__ a_s, float* __restrict__ a_d) {
    float ps[2] = {0.f, 0.f}, pd[2] = {0.f, 0.f};
#pragma unroll
    for (int q = 0; q < 32; ++q) {
        const int g = (C == 16 && q >= 16) ? 1 : 0;
        ps[g] += acc[q] * as_flat[j0u + q];
        pd[g] += acc[q] * ad_flat[j0u + q];
    }
    if (n < n_nodes) {
        __half2 buf[16];
#pragma unroll
        for (int q = 0; q < 16; ++q)
            buf[q] = __float22half2_rn(make_float2(acc[2 * q], acc[2 * q + 1]));
        float4* dst = (float4*)(xp + (size_t)n * HC + j0);
        const float4* srcb = (const float4*)buf;
#pragma unroll
        for (int q = 0; q < 4; ++q) dst[q] = srcb[q];
        if (C == 32) {
            const int h = j0 / 32;
            a_s[(size_t)n * NHEAD + h] = ps[0];
            a_d[(size_t)n * NHEAD + h] = pd[0];
        } else {
            const int h = j0 / 16;
            a_s[(size_t)n * NHEAD + h] = ps[0];
            a_s[(size_t)n * NHEAD + h + 1] = ps[1];
            a_d[(size_t)n * NHEAD + h] = pd[0];
            a_d[(size_t)n * NHEAD + h + 1] = pd[1];
        }
    }
}

template<int DIN, int HC, int C>
__global__ __launch_bounds__(256) void proj_kernel(
    const float* __restrict__ xin, int xstride, int xoff,
    const float* __restrict__ W,
    const float* __restrict__ as_flat, const float* __restrict__ ad_flat,
    __half* __restrict__ xp, float* __restrict__ a_s, float* __restrict__ a_d,
    int n_nodes) {
    constexpr int KC = (DIN >= 32) ? 32 : DIN;   // k-chunk size
    constexpr int NC = DIN / KC;                 // #chunks (4 / 1 / 1)
    constexpr int DB = (NC > 1) ? 2 : 1;         // double-buffered?
    __shared__ float slds[DB * KC * 128];

    const int lane = threadIdx.x & 63;
    const int wv = threadIdx.x >> 6;
    const int j0 = blockIdx.x * 128 + wv * 32;
    const int j0u = __builtin_amdgcn_readfirstlane(j0);
    const int n0 = blockIdx.y * 128;
    const int nlast = n_nodes - 1;

    // staging roles: thread t loads KC/2 floats of row r (half rows per thread pair)
    const int t = threadIdx.x;
    const int sr = t >> 1;           // 0..127
    const int shalf = t & 1;
    const int srn = min(n0 + sr, nlast);
    const float* __restrict__ srow = xin + (size_t)srn * xstride + xoff + shalf * (KC / 2);

    auto stage = [&](int c, int b) {
        float* __restrict__ dst = slds + b * KC * 128;
        const float* __restrict__ src = srow + c * KC;
#pragma unroll
        for (int q = 0; q < KC / 8; ++q) {
            const float4 v = *(const float4*)(src + q * 4);
            const int kb = shalf * (KC / 2) + q * 4;
            dst[(kb + 0) * 128 + sr] = v.x;
            dst[(kb + 1) * 128 + sr] = v.y;
            dst[(kb + 2) * 128 + sr] = v.z;
            dst[(kb + 3) * 128 + sr] = v.w;
        }
    };

    float acc0[32], acc1[32];
#pragma unroll
    for (int q = 0; q < 32; ++q) { acc0[q] = 0.f; acc1[q] = 0.f; }

    const float* __restrict__ Wj = W + j0u;

    stage(0, 0);
    __syncthreads();

#pragma unroll
    for (int c = 0; c < NC; ++c) {
        if (DB == 2 && c + 1 < NC) stage(c + 1, (c + 1) & 1);
        const float* __restrict__ sb = slds + (DB == 2 ? (c & 1) : 0) * KC * 128;
#pragma unroll
        for (int k = 0; k < KC; ++k) {
            const float xk0 = sb[k * 128 + lane];
            const float xk1 = sb[k * 128 + 64 + lane];
            const float4* __restrict__ W4 =
                (const float4*)(Wj + (size_t)(c * KC + k) * HC);
#pragma unroll
            for (int q = 0; q < 8; ++q) {
                const float4 wq = W4[q];
                acc0[q * 4 + 0] += xk0 * wq.x;  acc1[q * 4 + 0] += xk1 * wq.x;
                acc0[q * 4 + 1] += xk0 * wq.y;  acc1[q * 4 + 1] += xk1 * wq.y;
                acc0[q * 4 + 2] += xk0 * wq.z;  acc1[q * 4 + 2] += xk1 * wq.z;
                acc0[q * 4 + 3] += xk0 * wq.w;  acc1[q * 4 + 3] += xk1 * wq.w;
            }
        }
        if (DB == 2 && c + 1 < NC) __syncthreads();
    }

    proj_epilogue<HC, C>(acc0, n0 + lane, n_nodes, j0, j0u, as_flat, ad_flat, xp, a_s, a_d);
    proj_epilogue<HC, C>(acc1, n0 + 64 + lane, n_nodes, j0, j0u, as_flat, ad_flat, xp, a_s, a_d);
}

// ---------------- CSR build ----------------
__global__ void hist_kernel(const int* __restrict__ ei, int E, int* __restrict__ deg) {
    const int e = blockIdx.x * blockDim.x + threadIdx.x;
    if (e < E) atomicAdd(&deg[ei[E + e]], 1);
}

__global__ __launch_bounds__(256) void blocksum_kernel(const int* __restrict__ deg, int N,
                                                       int* __restrict__ bsum) {
    __shared__ int red[256];
    const int t = threadIdx.x;
    const int base = blockIdx.x * 1024 + t * 4;
    int s = 0;
    if (base + 3 < N) {
        const int4 v = *(const int4*)(deg + base);
        s = v.x + v.y + v.z + v.w;
    } else {
#pragma unroll
        for (int i = 0; i < 4; ++i) if (base + i < N) s += deg[base + i];
    }
    red[t] = s;
    __syncthreads();
    for (int off = 128; off > 0; off >>= 1) {
        if (t < off) red[t] += red[t + off];
        __syncthreads();
    }
    if (t == 0) bsum[blockIdx.x] = red[0];
}

__global__ __launch_bounds__(64) void bscan_kernel(int* __restrict__ bsum, int NB) {
    const int lane = threadIdx.x;
    int run = 0;
    for (int base = 0; base < NB; base += 64) {
        const int i = base + lane;
        const int v = (i < NB) ? bsum[i] : 0;
        int inc = v;
#pragma unroll
        for (int off = 1; off < 64; off <<= 1) {
            const int u = __shfl_up(inc, off, 64);
            if (lane >= off) inc += u;
        }
        if (i < NB) bsum[i] = run + inc - v;
        run += __shfl(inc, 63, 64);
    }
}

__global__ __launch_bounds__(256) void rowptr_kernel(const int* __restrict__ deg,
                                                     const int* __restrict__ bsum,
                                                     int N, int E,
                                                     int* __restrict__ rowptr,
                                                     int* __restrict__ cursor) {
    __shared__ int tsum[256];
    const int t = threadIdx.x;
    const int base = blockIdx.x * 1024 + t * 4;
    int v[4];
    int s = 0;
#pragma unroll
    for (int i = 0; i < 4; ++i) {
        v[i] = (base + i < N) ? deg[base + i] : 0;
        s += v[i];
    }
    tsum[t] = s;
    __syncthreads();
    for (int off = 1; off < 256; off <<= 1) {
        const int u = (t >= off) ? tsum[t - off] : 0;
        __syncthreads();
        tsum[t] += u;
        __syncthreads();
    }
    int run = bsum[blockIdx.x] + tsum[t] - s;
#pragma unroll
    for (int i = 0; i < 4; ++i) {
        if (base + i < N) {
            rowptr[base + i] = run;
            cursor[base + i] = run;
            run += v[i];
        }
    }
    if (blockIdx.x == 0 && t == 0) rowptr[N] = E;
}

__global__ void scatter_kernel(const int* __restrict__ ei, int E,
                               int* __restrict__ cursor, int* __restrict__ csr_src) {
    const int e = blockIdx.x * blockDim.x + threadIdx.x;
    if (e < E) {
        const int pos = atomicAdd(&cursor[ei[E + e]], 1);
        csr_src[pos] = ei[e];
    }
}

// ---------------- fused softmax+aggregation: one wave per dst ----------------
template<int C>
__global__ __launch_bounds__(256) void aggr_kernel(
    const int* __restrict__ rowptr, const int* __restrict__ csr_src,
    const float* __restrict__ a_s, const float* __restrict__ a_d,
    const __half* __restrict__ xp, const float* __restrict__ bias,
    float* __restrict__ out, int out_off, int N) {
    constexpr int HC = NHEAD * C;
    constexpr int LPE = HC / 8;     // lanes per edge-row (32 or 16)
    constexpr int EPW = 64 / LPE;   // edges in flight per wave (2 or 4)
    constexpr int CQ = C / 8;       // c-octs per head (4 or 2)
    const int n = (blockIdx.x * blockDim.x + threadIdx.x) >> 6;
    if (n >= N) return;
    const int lane = threadIdx.x & 63;
    const int iA = lane >> 3, hA = lane & 7;        // phase-A role
    const int le = lane & (LPE - 1);                // phase-B role
    const int epar = lane / LPE;
    const int h = le / CQ;
    const int c0 = (le % CQ) * 8;
    const int row0 = rowptr[n];
    const int deg = rowptr[n + 1] - row0;
    const int items = deg + 1;                      // + self-loop

    const float adhA = a_d[(size_t)n * NHEAD + hA];
    float sacc = 0.f;
    float acc[8];
#pragma unroll
    for (int j = 0; j < 8; ++j) acc[j] = 0.f;

    for (int base = 0; base < items; base += 8) {
        const int idx = base + iA;
        int src = n;
        float ex = 0.f;
        if (idx < items) {
            if (idx < deg) src = csr_src[row0 + idx];
            ex = expf(lrelu(a_s[(size_t)src * NHEAD + hA] + adhA));
        }
        sacc += ex;
        const int cnt = min(items - base, 8);
        for (int g = 0; g < cnt; g += EPW) {
            const int it = g + epar;
            const int srcb = __shfl(src, it * 8, 64);
            const float exb = __shfl(ex, it * 8 + h, 64);
            if (it < cnt) {
                const float4 r = *(const float4*)(xp + (size_t)srcb * HC + h * C + c0);
                const __half2* h2 = (const __half2*)&r;
#pragma unroll
                for (int q = 0; q < 4; ++q) {
                    const float2 f = __half22float2(h2[q]);
                    acc[2 * q]     += exb * f.x;
                    acc[2 * q + 1] += exb * f.y;
                }
            }
        }
    }
    // softmax denominators: reduce over slots -> lane L holds s for head L&7
    sacc += __shfl_xor(sacc, 8, 64);
    sacc += __shfl_xor(sacc, 16, 64);
    sacc += __shfl_xor(sacc, 32, 64);
    const float sinv = 1.f / __shfl(sacc, h, 64);

    // combine edge-parallel copies (same (h,c-oct), different edge subsets)
#pragma unroll
    for (int off = LPE; off < 64; off <<= 1) {
#pragma unroll
        for (int j = 0; j < 8; ++j) acc[j] += __shfl_xor(acc[j], off, 64);
    }
#pragma unroll
    for (int j = 0; j < 8; ++j) acc[j] *= sinv;      // per-head normalize
    // head-mean reduce (over h lanes)
#pragma unroll
    for (int off = CQ; off < LPE; off <<= 1) {
#pragma unroll
        for (int j = 0; j < 8; ++j) acc[j] += __shfl_xor(acc[j], off, 64);
    }
    if (lane < CQ) {
        float v[8];
#pragma unroll
        for (int j = 0; j < 8; ++j)
            v[j] = fmaxf(acc[j] * (1.f / NHEAD) + bias[lane * 8 + j], 0.f);
        float* op = out + (size_t)n * OUT_COLS + out_off + lane * 8;
        *(float4*)op = make_float4(v[0], v[1], v[2], v[3]);
        *(float4*)(op + 4) = make_float4(v[4], v[5], v[6], v[7]);
    }
}

static inline size_t align_up(size_t x) { return (x + 255) & ~size_t(255); }

extern "C" void kernel_launch(void* const* d_in, const int* in_sizes, int n_in,
                              void* d_out, int out_size, void* d_ws, size_t ws_size,
                              hipStream_t stream) {
    const float* x  = (const float*)d_in[0];
    const int*   ei = (const int*)d_in[1];
    const float* W1  = (const float*)d_in[2];
    const float* as1 = (const float*)d_in[3];
    const float* ad1 = (const float*)d_in[4];
    const float* b1  = (const float*)d_in[5];
    const float* W2  = (const float*)d_in[6];
    const float* as2 = (const float*)d_in[7];
    const float* ad2 = (const float*)d_in[8];
    const float* b2  = (const float*)d_in[9];
    const float* W3  = (const float*)d_in[10];
    const float* as3 = (const float*)d_in[11];
    const float* ad3 = (const float*)d_in[12];
    const float* b3  = (const float*)d_in[13];
    float* out = (float*)d_out;

    const int N = in_sizes[0] / 128;
    const int E = in_sizes[1] / 2;

    // workspace layout
    char* w = (char*)d_ws;
    __half* xp    = (__half*)w; w += align_up((size_t)N * 256 * 2);
    float* a_s    = (float*)w;  w += align_up((size_t)N * NHEAD * 4);
    float* a_d    = (float*)w;  w += align_up((size_t)N * NHEAD * 4);
    int*   deg    = (int*)w;    w += align_up((size_t)N * 4);
    int*   rowptr = (int*)w;    w += align_up((size_t)(N + 1) * 4);
    int*   cursor = (int*)w;    w += align_up((size_t)N * 4);
    int*   csrsrc = (int*)w;    w += align_up((size_t)E * 4);
    int*   bsum   = (int*)w;    w += align_up(((size_t)N / 1024 + 2) * 4);

    const int EB = 256;
    const int eg = (E + EB - 1) / EB;
    const int ntiles = (N + 127) / 128;     // 128 nodes per block (2 per lane)
    const int ngrid = (N + 3) / 4;          // 4 dst-waves per 256-thread block
    const int NB = (N + 1023) / 1024;       // scan chunks

    // ---- CSR build (once, reused by all 3 layers) ----
    hipMemsetAsync(deg, 0, (size_t)N * 4, stream);
    hist_kernel<<<eg, EB, 0, stream>>>(ei, E, deg);
    blocksum_kernel<<<NB, 256, 0, stream>>>(deg, N, bsum);
    bscan_kernel<<<1, 64, 0, stream>>>(bsum, NB);
    rowptr_kernel<<<NB, 256, 0, stream>>>(deg, bsum, N, E, rowptr, cursor);
    scatter_kernel<<<eg, EB, 0, stream>>>(ei, E, cursor, csrsrc);

    // ---------------- Layer 1: din=128, C=32, HC=256 ----------------
    proj_kernel<128, 256, 32><<<dim3(2, ntiles), 256, 0, stream>>>(
        x, 128, 0, W1, as1, ad1, xp, a_s, a_d, N);
    aggr_kernel<32><<<ngrid, 256, 0, stream>>>(rowptr, csrsrc, a_s, a_d, xp, b1, out, 0, N);

    // ---------------- Layer 2: din=32, C=16, HC=128 (input = out[:,0:32]) ----------------
    proj_kernel<32, 128, 16><<<dim3(1, ntiles), 256, 0, stream>>>(
        out, OUT_COLS, 0, W2, as2, ad2, xp, a_s, a_d, N);
    aggr_kernel<16><<<ngrid, 256, 0, stream>>>(rowptr, csrsrc, a_s, a_d, xp, b2, out, 32, N);

    // ---------------- Layer 3: din=16, C=32, HC=256 (input = out[:,32:48]) ----------------
    proj_kernel<16, 256, 32><<<dim3(2, ntiles), 256, 0, stream>>>(
        out, OUT_COLS, 32, W3, as3, ad3, xp, a_s, a_d, N);
    aggr_kernel<32><<<ngrid, 256, 0, stream>>>(rowptr, csrsrc, a_s, a_d, xp, b3, out, 48, N);
}

// Round 9
// 260.379 us; speedup vs baseline: 3.5067x; 3.5067x over previous
//
#include <hip/hip_runtime.h>
#include <hip/hip_fp16.h>
#include <math.h>

#define NHEAD 8
#define NEG_SLOPE 0.2f
#define OUT_COLS 80

__device__ __forceinline__ float lrelu(float x) {
    return x > 0.f ? x : NEG_SLOPE * x;
}

// ---------------- projection: outer-product tile, 2 nodes per lane (R6 structure) ----------------
// Block = 4 waves. Wave: 128 nodes (lane -> n, n+64) x 32 cols. xp stored fp16 [n][h*C+c].
// Fully-unrolled k loop with compile-time W offsets: compiler schedules x/W loads itself.
template<int HC, int C>
__device__ __forceinline__ void proj_epilogue(
    const float (&acc)[32], int n, int n_nodes, int j0, int j0u,
    const float* __restrict__ as_flat, const float* __restrict__ ad_flat,
    __half* __restrict__ xp, float* __restrict__ a_s, float* __restrict__ a_d) {
    float ps[2] = {0.f, 0.f}, pd[2] = {0.f, 0.f};
#pragma unroll
    for (int q = 0; q < 32; ++q) {
        const int g = (C == 16 && q >= 16) ? 1 : 0;
        ps[g] += acc[q] * as_flat[j0u + q];
        pd[g] += acc[q] * ad_flat[j0u + q];
    }
    if (n < n_nodes) {
        __half2 buf[16];
#pragma unroll
        for (int q = 0; q < 16; ++q)
            buf[q] = __float22half2_rn(make_float2(acc[2 * q], acc[2 * q + 1]));
        float4* dst = (float4*)(xp + (size_t)n * HC + j0);
        const float4* srcb = (const float4*)buf;
#pragma unroll
        for (int q = 0; q < 4; ++q) dst[q] = srcb[q];
        if (C == 32) {
            const int h = j0 / 32;
            a_s[(size_t)n * NHEAD + h] = ps[0];
            a_d[(size_t)n * NHEAD + h] = pd[0];
        } else {
            const int h = j0 / 16;
            a_s[(size_t)n * NHEAD + h] = ps[0];
            a_s[(size_t)n * NHEAD + h + 1] = ps[1];
            a_d[(size_t)n * NHEAD + h] = pd[0];
            a_d[(size_t)n * NHEAD + h + 1] = pd[1];
        }
    }
}

template<int DIN, int HC, int C>
__global__ __launch_bounds__(256) void proj_kernel(
    const float* __restrict__ xin, int xstride, int xoff,
    const float* __restrict__ W,
    const float* __restrict__ as_flat, const float* __restrict__ ad_flat,
    __half* __restrict__ xp, float* __restrict__ a_s, float* __restrict__ a_d,
    int n_nodes) {
    const int lane = threadIdx.x & 63;
    const int wv = threadIdx.x >> 6;
    const int j0 = blockIdx.x * 128 + wv * 32;
    const int j0u = __builtin_amdgcn_readfirstlane(j0);
    const int n0 = blockIdx.y * 128 + lane;
    const int nlast = n_nodes - 1;
    const int nc0 = min(n0, nlast);
    const int nc1 = min(n0 + 64, nlast);

    float acc0[32], acc1[32];
#pragma unroll
    for (int q = 0; q < 32; ++q) { acc0[q] = 0.f; acc1[q] = 0.f; }

    const float* __restrict__ xr0 = xin + (size_t)nc0 * xstride + xoff;
    const float* __restrict__ xr1 = xin + (size_t)nc1 * xstride + xoff;

#pragma unroll 2
    for (int k4 = 0; k4 < DIN / 4; ++k4) {
        const float4 xv0 = *(const float4*)(xr0 + k4 * 4);
        const float4 xv1 = *(const float4*)(xr1 + k4 * 4);
#pragma unroll
        for (int kk = 0; kk < 4; ++kk) {
            const float xk0 = kk == 0 ? xv0.x : kk == 1 ? xv0.y : kk == 2 ? xv0.z : xv0.w;
            const float xk1 = kk == 0 ? xv1.x : kk == 1 ? xv1.y : kk == 2 ? xv1.z : xv1.w;
            const float4* __restrict__ W4 =
                (const float4*)(W + (size_t)(k4 * 4 + kk) * HC + j0u);
#pragma unroll
            for (int q = 0; q < 8; ++q) {
                const float4 wq = W4[q];
                acc0[q * 4 + 0] += xk0 * wq.x;  acc1[q * 4 + 0] += xk1 * wq.x;
                acc0[q * 4 + 1] += xk0 * wq.y;  acc1[q * 4 + 1] += xk1 * wq.y;
                acc0[q * 4 + 2] += xk0 * wq.z;  acc1[q * 4 + 2] += xk1 * wq.z;
                acc0[q * 4 + 3] += xk0 * wq.w;  acc1[q * 4 + 3] += xk1 * wq.w;
            }
        }
    }
    proj_epilogue<HC, C>(acc0, n0, n_nodes, j0, j0u, as_flat, ad_flat, xp, a_s, a_d);
    proj_epilogue<HC, C>(acc1, n0 + 64, n_nodes, j0, j0u, as_flat, ad_flat, xp, a_s, a_d);
}

// ---------------- CSR build ----------------
__global__ void hist_kernel(const int* __restrict__ ei, int E, int* __restrict__ deg) {
    const int e = blockIdx.x * blockDim.x + threadIdx.x;
    if (e < E) atomicAdd(&deg[ei[E + e]], 1);
}

__global__ __launch_bounds__(256) void blocksum_kernel(const int* __restrict__ deg, int N,
                                                       int* __restrict__ bsum) {
    __shared__ int red[256];
    const int t = threadIdx.x;
    const int base = blockIdx.x * 1024 + t * 4;
    int s = 0;
    if (base + 3 < N) {
        const int4 v = *(const int4*)(deg + base);
        s = v.x + v.y + v.z + v.w;
    } else {
#pragma unroll
        for (int i = 0; i < 4; ++i) if (base + i < N) s += deg[base + i];
    }
    red[t] = s;
    __syncthreads();
    for (int off = 128; off > 0; off >>= 1) {
        if (t < off) red[t] += red[t + off];
        __syncthreads();
    }
    if (t == 0) bsum[blockIdx.x] = red[0];
}

__global__ __launch_bounds__(64) void bscan_kernel(int* __restrict__ bsum, int NB) {
    const int lane = threadIdx.x;
    int run = 0;
    for (int base = 0; base < NB; base += 64) {
        const int i = base + lane;
        const int v = (i < NB) ? bsum[i] : 0;
        int inc = v;
#pragma unroll
        for (int off = 1; off < 64; off <<= 1) {
            const int u = __shfl_up(inc, off, 64);
            if (lane >= off) inc += u;
        }
        if (i < NB) bsum[i] = run + inc - v;
        run += __shfl(inc, 63, 64);
    }
}

__global__ __launch_bounds__(256) void rowptr_kernel(const int* __restrict__ deg,
                                                     const int* __restrict__ bsum,
                                                     int N, int E,
                                                     int* __restrict__ rowptr,
                                                     int* __restrict__ cursor) {
    __shared__ int tsum[256];
    const int t = threadIdx.x;
    const int base = blockIdx.x * 1024 + t * 4;
    int v[4];
    int s = 0;
#pragma unroll
    for (int i = 0; i < 4; ++i) {
        v[i] = (base + i < N) ? deg[base + i] : 0;
        s += v[i];
    }
    tsum[t] = s;
    __syncthreads();
    for (int off = 1; off < 256; off <<= 1) {
        const int u = (t >= off) ? tsum[t - off] : 0;
        __syncthreads();
        tsum[t] += u;
        __syncthreads();
    }
    int run = bsum[blockIdx.x] + tsum[t] - s;
#pragma unroll
    for (int i = 0; i < 4; ++i) {
        if (base + i < N) {
            rowptr[base + i] = run;
            cursor[base + i] = run;
            run += v[i];
        }
    }
    if (blockIdx.x == 0 && t == 0) rowptr[N] = E;
}

__global__ void scatter_kernel(const int* __restrict__ ei, int E,
                               int* __restrict__ cursor, int* __restrict__ csr_src) {
    const int e = blockIdx.x * blockDim.x + threadIdx.x;
    if (e < E) {
        const int pos = atomicAdd(&cursor[ei[E + e]], 1);
        csr_src[pos] = ei[e];
    }
}

// ---------------- fused softmax+aggregation: one wave per dst ----------------
// Items = deg edges + 1 self-loop. Phase A: lane=(slot,head) computes unnormalized ex.
// Phase B: unconditional, fully-unrolled gather rounds -- invalid slots carry
// src=n (valid addr) and ex=0 (no contribution), so all EPW-strided row loads
// issue back-to-back -> 4x memory-level parallelism on the random xp gathers.
template<int C>
__global__ __launch_bounds__(256) void aggr_kernel(
    const int* __restrict__ rowptr, const int* __restrict__ csr_src,
    const float* __restrict__ a_s, const float* __restrict__ a_d,
    const __half* __restrict__ xp, const float* __restrict__ bias,
    float* __restrict__ out, int out_off, int N) {
    constexpr int HC = NHEAD * C;
    constexpr int LPE = HC / 8;     // lanes per edge-row (32 or 16)
    constexpr int EPW = 64 / LPE;   // edges in flight per wave (2 or 4)
    constexpr int CQ = C / 8;       // c-octs per head (4 or 2)
    const int n = (blockIdx.x * blockDim.x + threadIdx.x) >> 6;
    if (n >= N) return;
    const int lane = threadIdx.x & 63;
    const int iA = lane >> 3, hA = lane & 7;        // phase-A role
    const int le = lane & (LPE - 1);                // phase-B role
    const int epar = lane / LPE;
    const int h = le / CQ;
    const int c0 = (le % CQ) * 8;
    const int row0 = rowptr[n];
    const int deg = rowptr[n + 1] - row0;
    const int items = deg + 1;                      // + self-loop

    const float adhA = a_d[(size_t)n * NHEAD + hA];
    float sacc = 0.f;
    float acc[8];
#pragma unroll
    for (int j = 0; j < 8; ++j) acc[j] = 0.f;

    for (int base = 0; base < items; base += 8) {
        const int idx = base + iA;
        int src = n;
        float ex = 0.f;
        if (idx < items) {
            if (idx < deg) src = csr_src[row0 + idx];
            ex = expf(lrelu(a_s[(size_t)src * NHEAD + hA] + adhA));
        }
        sacc += ex;
#pragma unroll
        for (int g = 0; g < 8; g += EPW) {
            const int it = g + epar;
            const int srcb = __shfl(src, it * 8, 64);
            const float exb = __shfl(ex, it * 8 + h, 64);
            const float4 r = *(const float4*)(xp + (size_t)srcb * HC + h * C + c0);
            const __half2* h2 = (const __half2*)&r;
#pragma unroll
            for (int q = 0; q < 4; ++q) {
                const float2 f = __half22float2(h2[q]);
                acc[2 * q]     += exb * f.x;
                acc[2 * q + 1] += exb * f.y;
            }
        }
    }
    // softmax denominators: reduce over slots -> lane L holds s for head L&7
    sacc += __shfl_xor(sacc, 8, 64);
    sacc += __shfl_xor(sacc, 16, 64);
    sacc += __shfl_xor(sacc, 32, 64);
    const float sinv = 1.f / __shfl(sacc, h, 64);

    // combine edge-parallel copies (same (h,c-oct), different edge subsets)
#pragma unroll
    for (int off = LPE; off < 64; off <<= 1) {
#pragma unroll
        for (int j = 0; j < 8; ++j) acc[j] += __shfl_xor(acc[j], off, 64);
    }
#pragma unroll
    for (int j = 0; j < 8; ++j) acc[j] *= sinv;      // per-head normalize
    // head-mean reduce (over h lanes)
#pragma unroll
    for (int off = CQ; off < LPE; off <<= 1) {
#pragma unroll
        for (int j = 0; j < 8; ++j) acc[j] += __shfl_xor(acc[j], off, 64);
    }
    if (lane < CQ) {
        float v[8];
#pragma unroll
        for (int j = 0; j < 8; ++j)
            v[j] = fmaxf(acc[j] * (1.f / NHEAD) + bias[lane * 8 + j], 0.f);
        float* op = out + (size_t)n * OUT_COLS + out_off + lane * 8;
        *(float4*)op = make_float4(v[0], v[1], v[2], v[3]);
        *(float4*)(op + 4) = make_float4(v[4], v[5], v[6], v[7]);
    }
}

static inline size_t align_up(size_t x) { return (x + 255) & ~size_t(255); }

extern "C" void kernel_launch(void* const* d_in, const int* in_sizes, int n_in,
                              void* d_out, int out_size, void* d_ws, size_t ws_size,
                              hipStream_t stream) {
    const float* x  = (const float*)d_in[0];
    const int*   ei = (const int*)d_in[1];
    const float* W1  = (const float*)d_in[2];
    const float* as1 = (const float*)d_in[3];
    const float* ad1 = (const float*)d_in[4];
    const float* b1  = (const float*)d_in[5];
    const float* W2  = (const float*)d_in[6];
    const float* as2 = (const float*)d_in[7];
    const float* ad2 = (const float*)d_in[8];
    const float* b2  = (const float*)d_in[9];
    const float* W3  = (const float*)d_in[10];
    const float* as3 = (const float*)d_in[11];
    const float* ad3 = (const float*)d_in[12];
    const float* b3  = (const float*)d_in[13];
    float* out = (float*)d_out;

    const int N = in_sizes[0] / 128;
    const int E = in_sizes[1] / 2;

    // workspace layout
    char* w = (char*)d_ws;
    __half* xp    = (__half*)w; w += align_up((size_t)N * 256 * 2);
    float* a_s    = (float*)w;  w += align_up((size_t)N * NHEAD * 4);
    float* a_d    = (float*)w;  w += align_up((size_t)N * NHEAD * 4);
    int*   deg    = (int*)w;    w += align_up((size_t)N * 4);
    int*   rowptr = (int*)w;    w += align_up((size_t)(N + 1) * 4);
    int*   cursor = (int*)w;    w += align_up((size_t)N * 4);
    int*   csrsrc = (int*)w;    w += align_up((size_t)E * 4);
    int*   bsum   = (int*)w;    w += align_up(((size_t)N / 1024 + 2) * 4);

    const int EB = 256;
    const int eg = (E + EB - 1) / EB;
    const int ntiles = (N + 127) / 128;     // 128 nodes per block (2 per lane)
    const int ngrid = (N + 3) / 4;          // 4 dst-waves per 256-thread block
    const int NB = (N + 1023) / 1024;       // scan chunks

    // ---- CSR build (once, reused by all 3 layers) ----
    hipMemsetAsync(deg, 0, (size_t)N * 4, stream);
    hist_kernel<<<eg, EB, 0, stream>>>(ei, E, deg);
    blocksum_kernel<<<NB, 256, 0, stream>>>(deg, N, bsum);
    bscan_kernel<<<1, 64, 0, stream>>>(bsum, NB);
    rowptr_kernel<<<NB, 256, 0, stream>>>(deg, bsum, N, E, rowptr, cursor);
    scatter_kernel<<<eg, EB, 0, stream>>>(ei, E, cursor, csrsrc);

    // ---------------- Layer 1: din=128, C=32, HC=256 ----------------
    proj_kernel<128, 256, 32><<<dim3(2, ntiles), 256, 0, stream>>>(
        x, 128, 0, W1, as1, ad1, xp, a_s, a_d, N);
    aggr_kernel<32><<<ngrid, 256, 0, stream>>>(rowptr, csrsrc, a_s, a_d, xp, b1, out, 0, N);

    // ---------------- Layer 2: din=32, C=16, HC=128 (input = out[:,0:32]) ----------------
    proj_kernel<32, 128, 16><<<dim3(1, ntiles), 256, 0, stream>>>(
        out, OUT_COLS, 0, W2, as2, ad2, xp, a_s, a_d, N);
    aggr_kernel<16><<<ngrid, 256, 0, stream>>>(rowptr, csrsrc, a_s, a_d, xp, b2, out, 32, N);

    // ---------------- Layer 3: din=16, C=32, HC=256 (input = out[:,32:48]) ----------------
    proj_kernel<16, 256, 32><<<dim3(2, ntiles), 256, 0, stream>>>(
        out, OUT_COLS, 32, W3, as3, ad3, xp, a_s, a_d, N);
    aggr_kernel<32><<<ngrid, 256, 0, stream>>>(rowptr, csrsrc, a_s, a_d, xp, b3, out, 48, N);
}

// Round 11
// 220.313 us; speedup vs baseline: 4.1444x; 1.1819x over previous
//
#include <hip/hip_runtime.h>
#include <hip/hip_fp16.h>
#include <math.h>

#define NHEAD 8
#define NEG_SLOPE 0.2f
#define OUT_COLS 80

typedef _Float16 f16x8 __attribute__((ext_vector_type(8)));
typedef float f32x4 __attribute__((ext_vector_type(4)));

__device__ __forceinline__ float lrelu(float x) {
    return x > 0.f ? x : NEG_SLOPE * x;
}

// ---------------- W fragment pre-swizzle ----------------
// B-frag layout for mfma_f32_16x16x32_f16:
//   elems 0-3: k = kc*32 + (lane>>4)*4 + j,      col = nt*16 + (lane&15)
//   elems 4-7: k = kc*32 + 16 + (lane>>4)*4 + (j-4)
// Wf[(kc*NT+nt)*64 + lane][8] as halves -> one coalesced float4 per lane.
// k >= DINLIM reads as 0 (K zero-padding for DIN=16 layers).
__device__ __forceinline__ void prep32_frag(const float* __restrict__ W,
                                            __half* __restrict__ Wf,
                                            int HC, int NT, int t, int DINLIM) {
    const int lane = t & 63, f = t >> 6;
    const int kc = f / NT, nt = f % NT;
    const int col = nt * 16 + (lane & 15);
    const int kb = kc * 32 + ((lane >> 4) << 2);
    __half v[8];
#pragma unroll
    for (int j = 0; j < 8; ++j) {
        const int k = kb + (j & 3) + ((j >> 2) << 4);
        v[j] = (k < DINLIM) ? __float2half(W[k * HC + col]) : __half(0.f);
    }
    *(float4*)(Wf + (size_t)t * 8) = *(float4*)&v[0];
}

__global__ __launch_bounds__(256) void prep_all(
    const float* __restrict__ W1, const float* __restrict__ W2,
    const float* __restrict__ W3,
    __half* __restrict__ Wf1, __half* __restrict__ Wf2, __half* __restrict__ Wf3) {
    const int b = blockIdx.x, tid = threadIdx.x;
    if (b < 16) {                       // L1: 4 kc x 16 nt x 64 = 4096 frag-threads
        prep32_frag(W1, Wf1, 256, 16, b * 256 + tid, 128);
    } else if (b < 18) {                // L2: 1 kc x 8 nt x 64 = 512
        const int t = (b - 16) * 256 + tid;
        if (t < 512) prep32_frag(W2, Wf2, 128, 8, t, 32);
    } else {                            // L3: 1 kc x 16 nt x 64 = 1024 (K zero-padded)
        const int t = (b - 18) * 256 + tid;
        if (t < 1024) prep32_frag(W3, Wf3, 256, 16, t, 16);
    }
}

// ---------------- projection via MFMA ----------------
// Block = 4 waves; wave = 16 nodes x all HC cols, K via 16x16x32 (zero-padded for DIN=16).
// Epilogue: LDS transpose (row stride HC+8 halves keeps float4 16B-aligned),
// coalesced fp16 xp writeout fused with a_s/a_d dots.
template<int DIN, int HC, int C>
__global__ __launch_bounds__(256) void proj_mfma(
    const float* __restrict__ xin, int xstride, int xoff,
    const __half* __restrict__ Wf,
    const float* __restrict__ as_flat, const float* __restrict__ ad_flat,
    __half* __restrict__ xp, float* __restrict__ a_s, float* __restrict__ a_d,
    int n_nodes) {
    constexpr int NT = HC / 16;
    __shared__ __half lds[4][16][HC + 8];
    const int lane = threadIdx.x & 63;
    const int wv = threadIdx.x >> 6;
    const int n0 = (blockIdx.x * 4 + wv) * 16;
    const int nlast = n_nodes - 1;
    const int ar = min(n0 + (lane & 15), nlast);
    const int kb = (lane >> 4) << 2;
    const float* __restrict__ xr = xin + (size_t)ar * xstride + xoff;

    f32x4 acc[NT];
#pragma unroll
    for (int nt = 0; nt < NT; ++nt) acc[nt] = (f32x4){0.f, 0.f, 0.f, 0.f};

    if constexpr (DIN >= 32) {
        constexpr int KCNT = DIN / 32;
#pragma unroll
        for (int kc = 0; kc < KCNT; ++kc) {
            const float4 xv0 = *(const float4*)(xr + kc * 32 + kb);
            const float4 xv1 = *(const float4*)(xr + kc * 32 + 16 + kb);
            f16x8 af;
            af[0] = (_Float16)xv0.x; af[1] = (_Float16)xv0.y;
            af[2] = (_Float16)xv0.z; af[3] = (_Float16)xv0.w;
            af[4] = (_Float16)xv1.x; af[5] = (_Float16)xv1.y;
            af[6] = (_Float16)xv1.z; af[7] = (_Float16)xv1.w;
            const __half* __restrict__ Wb = Wf + ((size_t)kc * NT * 64 + lane) * 8;
#pragma unroll
            for (int nt = 0; nt < NT; ++nt) {
                const f16x8 bf = *(const f16x8*)(Wb + (size_t)nt * 64 * 8);
                acc[nt] = __builtin_amdgcn_mfma_f32_16x16x32_f16(af, bf, acc[nt], 0, 0, 0);
            }
        }
    } else {
        // DIN=16: K zero-padded to 32 (Wf elems for k>=16 are 0)
        const float4 xv0 = *(const float4*)(xr + kb);
        f16x8 af;
        af[0] = (_Float16)xv0.x; af[1] = (_Float16)xv0.y;
        af[2] = (_Float16)xv0.z; af[3] = (_Float16)xv0.w;
        af[4] = (_Float16)0.f; af[5] = (_Float16)0.f;
        af[6] = (_Float16)0.f; af[7] = (_Float16)0.f;
        const __half* __restrict__ Wb = Wf + (size_t)lane * 8;
#pragma unroll
        for (int nt = 0; nt < NT; ++nt) {
            const f16x8 bf = *(const f16x8*)(Wb + (size_t)nt * 64 * 8);
            acc[nt] = __builtin_amdgcn_mfma_f32_16x16x32_f16(af, bf, acc[nt], 0, 0, 0);
        }
    }

    // C-frag -> LDS (col = lane&15 within nt, rows kb..kb+3)
#pragma unroll
    for (int nt = 0; nt < NT; ++nt) {
#pragma unroll
        for (int r = 0; r < 4; ++r)
            lds[wv][kb + r][nt * 16 + (lane & 15)] = __float2half(acc[nt][r]);
    }

    // coalesced writeout + attention dots
    constexpr int F4PR = HC / 8;            // float4 chunks per row
    constexpr int ITER = 16 * F4PR / 64;
    constexpr int LPH = C / 8;              // lanes per (row, head)
#pragma unroll
    for (int i = 0; i < ITER; ++i) {
        const int flat = i * 64 + lane;
        const int row = flat / F4PR;
        const int co = (flat % F4PR) * 8;
        const int node = n0 + row;
        __half hv[8];
        *(float4*)hv = *(const float4*)&lds[wv][row][co];
        const float4 as0 = *(const float4*)(as_flat + co);
        const float4 as1 = *(const float4*)(as_flat + co + 4);
        const float4 ad0 = *(const float4*)(ad_flat + co);
        const float4 ad1 = *(const float4*)(ad_flat + co + 4);
        float xv[8];
#pragma unroll
        for (int j = 0; j < 8; ++j) xv[j] = __half2float(hv[j]);
        float ps = xv[0] * as0.x + xv[1] * as0.y + xv[2] * as0.z + xv[3] * as0.w
                 + xv[4] * as1.x + xv[5] * as1.y + xv[6] * as1.z + xv[7] * as1.w;
        float pd = xv[0] * ad0.x + xv[1] * ad0.y + xv[2] * ad0.z + xv[3] * ad0.w
                 + xv[4] * ad1.x + xv[5] * ad1.y + xv[6] * ad1.z + xv[7] * ad1.w;
#pragma unroll
        for (int off = 1; off < LPH; off <<= 1) {
            ps += __shfl_xor(ps, off, 64);
            pd += __shfl_xor(pd, off, 64);
        }
        if (node <= nlast) {
            *(float4*)(xp + (size_t)node * HC + co) = *(float4*)hv;
            if ((flat & (LPH - 1)) == 0) {
                const int h = co / C;
                a_s[(size_t)node * NHEAD + h] = ps;
                a_d[(size_t)node * NHEAD + h] = pd;
            }
        }
    }
}

// ---------------- CSR build ----------------
__global__ void hist_kernel(const int* __restrict__ ei, int E, int* __restrict__ deg) {
    const int e = blockIdx.x * blockDim.x + threadIdx.x;
    if (e < E) atomicAdd(&deg[ei[E + e]], 1);
}

__global__ __launch_bounds__(256) void blocksum_kernel(const int* __restrict__ deg, int N,
                                                       int* __restrict__ bsum) {
    __shared__ int red[256];
    const int t = threadIdx.x;
    const int base = blockIdx.x * 1024 + t * 4;
    int s = 0;
    if (base + 3 < N) {
        const int4 v = *(const int4*)(deg + base);
        s = v.x + v.y + v.z + v.w;
    } else {
#pragma unroll
        for (int i = 0; i < 4; ++i) if (base + i < N) s += deg[base + i];
    }
    red[t] = s;
    __syncthreads();
    for (int off = 128; off > 0; off >>= 1) {
        if (t < off) red[t] += red[t + off];
        __syncthreads();
    }
    if (t == 0) bsum[blockIdx.x] = red[0];
}

__global__ __launch_bounds__(64) void bscan_kernel(int* __restrict__ bsum, int NB) {
    const int lane = threadIdx.x;
    int run = 0;
    for (int base = 0; base < NB; base += 64) {
        const int i = base + lane;
        const int v = (i < NB) ? bsum[i] : 0;
        int inc = v;
#pragma unroll
        for (int off = 1; off < 64; off <<= 1) {
            const int u = __shfl_up(inc, off, 64);
            if (lane >= off) inc += u;
        }
        if (i < NB) bsum[i] = run + inc - v;
        run += __shfl(inc, 63, 64);
    }
}

__global__ __launch_bounds__(256) void rowptr_kernel(const int* __restrict__ deg,
                                                     const int* __restrict__ bsum,
                                                     int N, int E,
                                                     int* __restrict__ rowptr,
                                                     int* __restrict__ cursor) {
    __shared__ int tsum[256];
    const int t = threadIdx.x;
    const int base = blockIdx.x * 1024 + t * 4;
    int v[4];
    int s = 0;
#pragma unroll
    for (int i = 0; i < 4; ++i) {
        v[i] = (base + i < N) ? deg[base + i] : 0;
        s += v[i];
    }
    tsum[t] = s;
    __syncthreads();
    for (int off = 1; off < 256; off <<= 1) {
        const int u = (t >= off) ? tsum[t - off] : 0;
        __syncthreads();
        tsum[t] += u;
        __syncthreads();
    }
    int run = bsum[blockIdx.x] + tsum[t] - s;
#pragma unroll
    for (int i = 0; i < 4; ++i) {
        if (base + i < N) {
            rowptr[base + i] = run;
            cursor[base + i] = run;
            run += v[i];
        }
    }
    if (blockIdx.x == 0 && t == 0) rowptr[N] = E;
}

__global__ void scatter_kernel(const int* __restrict__ ei, int E,
                               int* __restrict__ cursor, int* __restrict__ csr_src) {
    const int e = blockIdx.x * blockDim.x + threadIdx.x;
    if (e < E) {
        const int pos = atomicAdd(&cursor[ei[E + e]], 1);
        csr_src[pos] = ei[e];
    }
}

// ---------------- fused softmax+aggregation: one wave per dst (R9-verbatim) ----------------
template<int C>
__global__ __launch_bounds__(256) void aggr_kernel(
    const int* __restrict__ rowptr, const int* __restrict__ csr_src,
    const float* __restrict__ a_s, const float* __restrict__ a_d,
    const __half* __restrict__ xp, const float* __restrict__ bias,
    float* __restrict__ out, int out_off, int N) {
    constexpr int HC = NHEAD * C;
    constexpr int LPE = HC / 8;     // lanes per edge-row (32 or 16)
    constexpr int EPW = 64 / LPE;   // edges in flight per wave (2 or 4)
    constexpr int CQ = C / 8;       // c-octs per head (4 or 2)
    const int n = (blockIdx.x * blockDim.x + threadIdx.x) >> 6;
    if (n >= N) return;
    const int lane = threadIdx.x & 63;
    const int iA = lane >> 3, hA = lane & 7;        // phase-A role
    const int le = lane & (LPE - 1);                // phase-B role
    const int epar = lane / LPE;
    const int h = le / CQ;
    const int c0 = (le % CQ) * 8;
    const int row0 = rowptr[n];
    const int deg = rowptr[n + 1] - row0;
    const int items = deg + 1;                      // + self-loop

    const float adhA = a_d[(size_t)n * NHEAD + hA];
    float sacc = 0.f;
    float acc[8];
#pragma unroll
    for (int j = 0; j < 8; ++j) acc[j] = 0.f;

    for (int base = 0; base < items; base += 8) {
        const int idx = base + iA;
        int src = n;
        float ex = 0.f;
        if (idx < items) {
            if (idx < deg) src = csr_src[row0 + idx];
            ex = expf(lrelu(a_s[(size_t)src * NHEAD + hA] + adhA));
        }
        sacc += ex;
#pragma unroll
        for (int g = 0; g < 8; g += EPW) {
            const int it = g + epar;
            const int srcb = __shfl(src, it * 8, 64);
            const float exb = __shfl(ex, it * 8 + h, 64);
            const float4 r = *(const float4*)(xp + (size_t)srcb * HC + h * C + c0);
            const __half2* h2 = (const __half2*)&r;
#pragma unroll
            for (int q = 0; q < 4; ++q) {
                const float2 f = __half22float2(h2[q]);
                acc[2 * q]     += exb * f.x;
                acc[2 * q + 1] += exb * f.y;
            }
        }
    }
    sacc += __shfl_xor(sacc, 8, 64);
    sacc += __shfl_xor(sacc, 16, 64);
    sacc += __shfl_xor(sacc, 32, 64);
    const float sinv = 1.f / __shfl(sacc, h, 64);

#pragma unroll
    for (int off = LPE; off < 64; off <<= 1) {
#pragma unroll
        for (int j = 0; j < 8; ++j) acc[j] += __shfl_xor(acc[j], off, 64);
    }
#pragma unroll
    for (int j = 0; j < 8; ++j) acc[j] *= sinv;      // per-head normalize
#pragma unroll
    for (int off = CQ; off < LPE; off <<= 1) {
#pragma unroll
        for (int j = 0; j < 8; ++j) acc[j] += __shfl_xor(acc[j], off, 64);
    }
    if (lane < CQ) {
        float v[8];
#pragma unroll
        for (int j = 0; j < 8; ++j)
            v[j] = fmaxf(acc[j] * (1.f / NHEAD) + bias[lane * 8 + j], 0.f);
        float* op = out + (size_t)n * OUT_COLS + out_off + lane * 8;
        *(float4*)op = make_float4(v[0], v[1], v[2], v[3]);
        *(float4*)(op + 4) = make_float4(v[4], v[5], v[6], v[7]);
    }
}

static inline size_t align_up(size_t x) { return (x + 255) & ~size_t(255); }

extern "C" void kernel_launch(void* const* d_in, const int* in_sizes, int n_in,
                              void* d_out, int out_size, void* d_ws, size_t ws_size,
                              hipStream_t stream) {
    const float* x  = (const float*)d_in[0];
    const int*   ei = (const int*)d_in[1];
    const float* W1  = (const float*)d_in[2];
    const float* as1 = (const float*)d_in[3];
    const float* ad1 = (const float*)d_in[4];
    const float* b1  = (const float*)d_in[5];
    const float* W2  = (const float*)d_in[6];
    const float* as2 = (const float*)d_in[7];
    const float* ad2 = (const float*)d_in[8];
    const float* b2  = (const float*)d_in[9];
    const float* W3  = (const float*)d_in[10];
    const float* as3 = (const float*)d_in[11];
    const float* ad3 = (const float*)d_in[12];
    const float* b3  = (const float*)d_in[13];
    float* out = (float*)d_out;

    const int N = in_sizes[0] / 128;
    const int E = in_sizes[1] / 2;

    // workspace layout
    char* w = (char*)d_ws;
    __half* xp    = (__half*)w; w += align_up((size_t)N * 256 * 2);
    float* a_s    = (float*)w;  w += align_up((size_t)N * NHEAD * 4);
    float* a_d    = (float*)w;  w += align_up((size_t)N * NHEAD * 4);
    int*   deg    = (int*)w;    w += align_up((size_t)N * 4);
    int*   rowptr = (int*)w;    w += align_up((size_t)(N + 1) * 4);
    int*   cursor = (int*)w;    w += align_up((size_t)N * 4);
    int*   csrsrc = (int*)w;    w += align_up((size_t)E * 4);
    int*   bsum   = (int*)w;    w += align_up(((size_t)N / 1024 + 2) * 4);
    __half* Wf1   = (__half*)w; w += align_up((size_t)128 * 256 * 2);
    __half* Wf2   = (__half*)w; w += align_up((size_t)32 * 128 * 2);
    __half* Wf3   = (__half*)w; w += align_up((size_t)32 * 256 * 2);   // K zero-padded to 32

    const int EB = 256;
    const int eg = (E + EB - 1) / EB;
    const int pgrid = (N + 63) / 64;        // 64 nodes per block (16/wave)
    const int ngrid = (N + 3) / 4;          // 4 dst-waves per 256-thread block
    const int NB = (N + 1023) / 1024;       // scan chunks

    // ---- W fragment swizzle + CSR build (reused by all 3 layers) ----
    prep_all<<<22, 256, 0, stream>>>(W1, W2, W3, Wf1, Wf2, Wf3);
    (void)hipMemsetAsync(deg, 0, (size_t)N * 4, stream);
    hist_kernel<<<eg, EB, 0, stream>>>(ei, E, deg);
    blocksum_kernel<<<NB, 256, 0, stream>>>(deg, N, bsum);
    bscan_kernel<<<1, 64, 0, stream>>>(bsum, NB);
    rowptr_kernel<<<NB, 256, 0, stream>>>(deg, bsum, N, E, rowptr, cursor);
    scatter_kernel<<<eg, EB, 0, stream>>>(ei, E, cursor, csrsrc);

    // ---------------- Layer 1: din=128, C=32, HC=256 ----------------
    proj_mfma<128, 256, 32><<<pgrid, 256, 0, stream>>>(
        x, 128, 0, Wf1, as1, ad1, xp, a_s, a_d, N);
    aggr_kernel<32><<<ngrid, 256, 0, stream>>>(rowptr, csrsrc, a_s, a_d, xp, b1, out, 0, N);

    // ---------------- Layer 2: din=32, C=16, HC=128 (input = out[:,0:32]) ----------------
    proj_mfma<32, 128, 16><<<pgrid, 256, 0, stream>>>(
        out, OUT_COLS, 0, Wf2, as2, ad2, xp, a_s, a_d, N);
    aggr_kernel<16><<<ngrid, 256, 0, stream>>>(rowptr, csrsrc, a_s, a_d, xp, b2, out, 32, N);

    // ---------------- Layer 3: din=16, C=32, HC=256 (input = out[:,32:48]) ----------------
    proj_mfma<16, 256, 32><<<pgrid, 256, 0, stream>>>(
        out, OUT_COLS, 32, Wf3, as3, ad3, xp, a_s, a_d, N);
    aggr_kernel<32><<<ngrid, 256, 0, stream>>>(rowptr, csrsrc, a_s, a_d, xp, b3, out, 48, N);
}

// Round 12
// 213.890 us; speedup vs baseline: 4.2688x; 1.0300x over previous
//
#include <hip/hip_runtime.h>
#include <hip/hip_fp16.h>
#include <math.h>

#define NHEAD 8
#define NEG_SLOPE 0.2f
#define OUT_COLS 80

typedef _Float16 f16x8 __attribute__((ext_vector_type(8)));
typedef float f32x4 __attribute__((ext_vector_type(4)));

__device__ __forceinline__ float lrelu(float x) {
    return x > 0.f ? x : NEG_SLOPE * x;
}

// ---------------- W fragment pre-swizzle ----------------
// B-frag layout for mfma_f32_16x16x32_f16:
//   elems 0-3: k = kc*32 + (lane>>4)*4 + j,      col = nt*16 + (lane&15)
//   elems 4-7: k = kc*32 + 16 + (lane>>4)*4 + (j-4)
// Wf[(kc*NT+nt)*64 + lane][8] as halves -> one coalesced float4 per lane.
// k >= DINLIM reads as 0 (K zero-padding for DIN=16 layers).
__device__ __forceinline__ void prep32_frag(const float* __restrict__ W,
                                            __half* __restrict__ Wf,
                                            int HC, int NT, int t, int DINLIM) {
    const int lane = t & 63, f = t >> 6;
    const int kc = f / NT, nt = f % NT;
    const int col = nt * 16 + (lane & 15);
    const int kb = kc * 32 + ((lane >> 4) << 2);
    __half v[8];
#pragma unroll
    for (int j = 0; j < 8; ++j) {
        const int k = kb + (j & 3) + ((j >> 2) << 4);
        v[j] = (k < DINLIM) ? __float2half(W[k * HC + col]) : __half(0.f);
    }
    *(float4*)(Wf + (size_t)t * 8) = *(float4*)&v[0];
}

__global__ __launch_bounds__(256) void prep_all(
    const float* __restrict__ W1, const float* __restrict__ W2,
    const float* __restrict__ W3,
    __half* __restrict__ Wf1, __half* __restrict__ Wf2, __half* __restrict__ Wf3) {
    const int b = blockIdx.x, tid = threadIdx.x;
    if (b < 16) {                       // L1: 4 kc x 16 nt x 64 = 4096 frag-threads
        prep32_frag(W1, Wf1, 256, 16, b * 256 + tid, 128);
    } else if (b < 18) {                // L2: 1 kc x 8 nt x 64 = 512
        const int t = (b - 16) * 256 + tid;
        if (t < 512) prep32_frag(W2, Wf2, 128, 8, t, 32);
    } else {                            // L3: 1 kc x 16 nt x 64 = 1024 (K zero-padded)
        const int t = (b - 18) * 256 + tid;
        if (t < 1024) prep32_frag(W3, Wf3, 256, 16, t, 16);
    }
}

// ---------------- projection via MFMA ----------------
// Block = 4 waves; wave = 16 nodes x all HC cols, K via 16x16x32 (zero-padded for DIN=16).
// Epilogue: LDS transpose (row stride HC+8 halves keeps float4 16B-aligned),
// coalesced fp16 xp writeout fused with a_s/a_d dots.
template<int DIN, int HC, int C>
__global__ __launch_bounds__(256) void proj_mfma(
    const float* __restrict__ xin, int xstride, int xoff,
    const __half* __restrict__ Wf,
    const float* __restrict__ as_flat, const float* __restrict__ ad_flat,
    __half* __restrict__ xp, float* __restrict__ a_s, float* __restrict__ a_d,
    int n_nodes) {
    constexpr int NT = HC / 16;
    __shared__ __half lds[4][16][HC + 8];
    const int lane = threadIdx.x & 63;
    const int wv = threadIdx.x >> 6;
    const int n0 = (blockIdx.x * 4 + wv) * 16;
    const int nlast = n_nodes - 1;
    const int ar = min(n0 + (lane & 15), nlast);
    const int kb = (lane >> 4) << 2;
    const float* __restrict__ xr = xin + (size_t)ar * xstride + xoff;

    f32x4 acc[NT];
#pragma unroll
    for (int nt = 0; nt < NT; ++nt) acc[nt] = (f32x4){0.f, 0.f, 0.f, 0.f};

    if constexpr (DIN >= 32) {
        constexpr int KCNT = DIN / 32;
#pragma unroll
        for (int kc = 0; kc < KCNT; ++kc) {
            const float4 xv0 = *(const float4*)(xr + kc * 32 + kb);
            const float4 xv1 = *(const float4*)(xr + kc * 32 + 16 + kb);
            f16x8 af;
            af[0] = (_Float16)xv0.x; af[1] = (_Float16)xv0.y;
            af[2] = (_Float16)xv0.z; af[3] = (_Float16)xv0.w;
            af[4] = (_Float16)xv1.x; af[5] = (_Float16)xv1.y;
            af[6] = (_Float16)xv1.z; af[7] = (_Float16)xv1.w;
            const __half* __restrict__ Wb = Wf + ((size_t)kc * NT * 64 + lane) * 8;
#pragma unroll
            for (int nt = 0; nt < NT; ++nt) {
                const f16x8 bf = *(const f16x8*)(Wb + (size_t)nt * 64 * 8);
                acc[nt] = __builtin_amdgcn_mfma_f32_16x16x32_f16(af, bf, acc[nt], 0, 0, 0);
            }
        }
    } else {
        // DIN=16: K zero-padded to 32 (Wf elems for k>=16 are 0)
        const float4 xv0 = *(const float4*)(xr + kb);
        f16x8 af;
        af[0] = (_Float16)xv0.x; af[1] = (_Float16)xv0.y;
        af[2] = (_Float16)xv0.z; af[3] = (_Float16)xv0.w;
        af[4] = (_Float16)0.f; af[5] = (_Float16)0.f;
        af[6] = (_Float16)0.f; af[7] = (_Float16)0.f;
        const __half* __restrict__ Wb = Wf + (size_t)lane * 8;
#pragma unroll
        for (int nt = 0; nt < NT; ++nt) {
            const f16x8 bf = *(const f16x8*)(Wb + (size_t)nt * 64 * 8);
            acc[nt] = __builtin_amdgcn_mfma_f32_16x16x32_f16(af, bf, acc[nt], 0, 0, 0);
        }
    }

    // C-frag -> LDS (col = lane&15 within nt, rows kb..kb+3)
#pragma unroll
    for (int nt = 0; nt < NT; ++nt) {
#pragma unroll
        for (int r = 0; r < 4; ++r)
            lds[wv][kb + r][nt * 16 + (lane & 15)] = __float2half(acc[nt][r]);
    }

    // coalesced writeout + attention dots
    constexpr int F4PR = HC / 8;            // float4 chunks per row
    constexpr int ITER = 16 * F4PR / 64;
    constexpr int LPH = C / 8;              // lanes per (row, head)
#pragma unroll
    for (int i = 0; i < ITER; ++i) {
        const int flat = i * 64 + lane;
        const int row = flat / F4PR;
        const int co = (flat % F4PR) * 8;
        const int node = n0 + row;
        __half hv[8];
        *(float4*)hv = *(const float4*)&lds[wv][row][co];
        const float4 as0 = *(const float4*)(as_flat + co);
        const float4 as1 = *(const float4*)(as_flat + co + 4);
        const float4 ad0 = *(const float4*)(ad_flat + co);
        const float4 ad1 = *(const float4*)(ad_flat + co + 4);
        float xv[8];
#pragma unroll
        for (int j = 0; j < 8; ++j) xv[j] = __half2float(hv[j]);
        float ps = xv[0] * as0.x + xv[1] * as0.y + xv[2] * as0.z + xv[3] * as0.w
                 + xv[4] * as1.x + xv[5] * as1.y + xv[6] * as1.z + xv[7] * as1.w;
        float pd = xv[0] * ad0.x + xv[1] * ad0.y + xv[2] * ad0.z + xv[3] * ad0.w
                 + xv[4] * ad1.x + xv[5] * ad1.y + xv[6] * ad1.z + xv[7] * ad1.w;
#pragma unroll
        for (int off = 1; off < LPH; off <<= 1) {
            ps += __shfl_xor(ps, off, 64);
            pd += __shfl_xor(pd, off, 64);
        }
        if (node <= nlast) {
            *(float4*)(xp + (size_t)node * HC + co) = *(float4*)hv;
            if ((flat & (LPH - 1)) == 0) {
                const int h = co / C;
                a_s[(size_t)node * NHEAD + h] = ps;
                a_d[(size_t)node * NHEAD + h] = pd;
            }
        }
    }
}

// ---------------- CSR build ----------------
__global__ void hist_kernel(const int* __restrict__ ei, int E, int* __restrict__ deg) {
    const int e = blockIdx.x * blockDim.x + threadIdx.x;
    if (e < E) atomicAdd(&deg[ei[E + e]], 1);
}

__global__ __launch_bounds__(256) void blocksum_kernel(const int* __restrict__ deg, int N,
                                                       int* __restrict__ bsum) {
    __shared__ int red[256];
    const int t = threadIdx.x;
    const int base = blockIdx.x * 1024 + t * 4;
    int s = 0;
    if (base + 3 < N) {
        const int4 v = *(const int4*)(deg + base);
        s = v.x + v.y + v.z + v.w;
    } else {
#pragma unroll
        for (int i = 0; i < 4; ++i) if (base + i < N) s += deg[base + i];
    }
    red[t] = s;
    __syncthreads();
    for (int off = 128; off > 0; off >>= 1) {
        if (t < off) red[t] += red[t + off];
        __syncthreads();
    }
    if (t == 0) bsum[blockIdx.x] = red[0];
}

__global__ __launch_bounds__(64) void bscan_kernel(int* __restrict__ bsum, int NB) {
    const int lane = threadIdx.x;
    int run = 0;
    for (int base = 0; base < NB; base += 64) {
        const int i = base + lane;
        const int v = (i < NB) ? bsum[i] : 0;
        int inc = v;
#pragma unroll
        for (int off = 1; off < 64; off <<= 1) {
            const int u = __shfl_up(inc, off, 64);
            if (lane >= off) inc += u;
        }
        if (i < NB) bsum[i] = run + inc - v;
        run += __shfl(inc, 63, 64);
    }
}

__global__ __launch_bounds__(256) void rowptr_kernel(const int* __restrict__ deg,
                                                     const int* __restrict__ bsum,
                                                     int N, int E,
                                                     int* __restrict__ rowptr,
                                                     int* __restrict__ cursor) {
    __shared__ int tsum[256];
    const int t = threadIdx.x;
    const int base = blockIdx.x * 1024 + t * 4;
    int v[4];
    int s = 0;
#pragma unroll
    for (int i = 0; i < 4; ++i) {
        v[i] = (base + i < N) ? deg[base + i] : 0;
        s += v[i];
    }
    tsum[t] = s;
    __syncthreads();
    for (int off = 1; off < 256; off <<= 1) {
        const int u = (t >= off) ? tsum[t - off] : 0;
        __syncthreads();
        tsum[t] += u;
        __syncthreads();
    }
    int run = bsum[blockIdx.x] + tsum[t] - s;
#pragma unroll
    for (int i = 0; i < 4; ++i) {
        if (base + i < N) {
            rowptr[base + i] = run;
            cursor[base + i] = run;
            run += v[i];
        }
    }
    if (blockIdx.x == 0 && t == 0) rowptr[N] = E;
}

__global__ void scatter_kernel(const int* __restrict__ ei, int E,
                               int* __restrict__ cursor, int* __restrict__ csr_src) {
    const int e = blockIdx.x * blockDim.x + threadIdx.x;
    if (e < E) {
        const int pos = atomicAdd(&cursor[ei[E + e]], 1);
        csr_src[pos] = ei[e];
    }
}

// ---------------- fused softmax+aggregation: one wave per dst ----------------
// Phase A: lane=(slot,head) computes unnormalized ex (fast __expf).
// Phase B: unconditional gather rounds; packed fp16 FMA accumulators
// (unnormalized sums <= ~300, well within fp16 range; relative err ~2^-11).
template<int C>
__global__ __launch_bounds__(256) void aggr_kernel(
    const int* __restrict__ rowptr, const int* __restrict__ csr_src,
    const float* __restrict__ a_s, const float* __restrict__ a_d,
    const __half* __restrict__ xp, const float* __restrict__ bias,
    float* __restrict__ out, int out_off, int N) {
    constexpr int HC = NHEAD * C;
    constexpr int LPE = HC / 8;     // lanes per edge-row (32 or 16)
    constexpr int EPW = 64 / LPE;   // edges in flight per wave (2 or 4)
    constexpr int CQ = C / 8;       // c-octs per head (4 or 2)
    const int n = (blockIdx.x * blockDim.x + threadIdx.x) >> 6;
    if (n >= N) return;
    const int lane = threadIdx.x & 63;
    const int iA = lane >> 3, hA = lane & 7;        // phase-A role
    const int le = lane & (LPE - 1);                // phase-B role
    const int epar = lane / LPE;
    const int h = le / CQ;
    const int c0 = (le % CQ) * 8;
    const int row0 = rowptr[n];
    const int deg = rowptr[n + 1] - row0;
    const int items = deg + 1;                      // + self-loop

    const float adhA = a_d[(size_t)n * NHEAD + hA];
    float sacc = 0.f;
    __half2 acch[4];
#pragma unroll
    for (int j = 0; j < 4; ++j) acch[j] = __float2half2_rn(0.f);

    for (int base = 0; base < items; base += 8) {
        const int idx = base + iA;
        int src = n;
        float ex = 0.f;
        if (idx < items) {
            if (idx < deg) src = csr_src[row0 + idx];
            ex = __expf(lrelu(a_s[(size_t)src * NHEAD + hA] + adhA));
        }
        sacc += ex;
#pragma unroll
        for (int g = 0; g < 8; g += EPW) {
            const int it = g + epar;
            const int srcb = __shfl(src, it * 8, 64);
            const float exb = __shfl(ex, it * 8 + h, 64);
            const __half2 exh = __float2half2_rn(exb);
            const float4 r = *(const float4*)(xp + (size_t)srcb * HC + h * C + c0);
            const __half2* h2 = (const __half2*)&r;
#pragma unroll
            for (int q = 0; q < 4; ++q)
                acch[q] = __hfma2(exh, h2[q], acch[q]);
        }
    }
    // softmax denominators: reduce over slots -> lane L holds s for head L&7
    sacc += __shfl_xor(sacc, 8, 64);
    sacc += __shfl_xor(sacc, 16, 64);
    sacc += __shfl_xor(sacc, 32, 64);
    const float sinv = 1.f / __shfl(sacc, h, 64);

    // widen packed accumulators to fp32 for the cross-lane reductions
    float acc[8];
#pragma unroll
    for (int q = 0; q < 4; ++q) {
        const float2 f = __half22float2(acch[q]);
        acc[2 * q] = f.x;
        acc[2 * q + 1] = f.y;
    }

    // combine edge-parallel copies (same (h,c-oct), different edge subsets)
#pragma unroll
    for (int off = LPE; off < 64; off <<= 1) {
#pragma unroll
        for (int j = 0; j < 8; ++j) acc[j] += __shfl_xor(acc[j], off, 64);
    }
#pragma unroll
    for (int j = 0; j < 8; ++j) acc[j] *= sinv;      // per-head normalize
    // head-mean reduce (over h lanes)
#pragma unroll
    for (int off = CQ; off < LPE; off <<= 1) {
#pragma unroll
        for (int j = 0; j < 8; ++j) acc[j] += __shfl_xor(acc[j], off, 64);
    }
    if (lane < CQ) {
        float v[8];
#pragma unroll
        for (int j = 0; j < 8; ++j)
            v[j] = fmaxf(acc[j] * (1.f / NHEAD) + bias[lane * 8 + j], 0.f);
        float* op = out + (size_t)n * OUT_COLS + out_off + lane * 8;
        *(float4*)op = make_float4(v[0], v[1], v[2], v[3]);
        *(float4*)(op + 4) = make_float4(v[4], v[5], v[6], v[7]);
    }
}

static inline size_t align_up(size_t x) { return (x + 255) & ~size_t(255); }

extern "C" void kernel_launch(void* const* d_in, const int* in_sizes, int n_in,
                              void* d_out, int out_size, void* d_ws, size_t ws_size,
                              hipStream_t stream) {
    const float* x  = (const float*)d_in[0];
    const int*   ei = (const int*)d_in[1];
    const float* W1  = (const float*)d_in[2];
    const float* as1 = (const float*)d_in[3];
    const float* ad1 = (const float*)d_in[4];
    const float* b1  = (const float*)d_in[5];
    const float* W2  = (const float*)d_in[6];
    const float* as2 = (const float*)d_in[7];
    const float* ad2 = (const float*)d_in[8];
    const float* b2  = (const float*)d_in[9];
    const float* W3  = (const float*)d_in[10];
    const float* as3 = (const float*)d_in[11];
    const float* ad3 = (const float*)d_in[12];
    const float* b3  = (const float*)d_in[13];
    float* out = (float*)d_out;

    const int N = in_sizes[0] / 128;
    const int E = in_sizes[1] / 2;

    // workspace layout
    char* w = (char*)d_ws;
    __half* xp    = (__half*)w; w += align_up((size_t)N * 256 * 2);
    float* a_s    = (float*)w;  w += align_up((size_t)N * NHEAD * 4);
    float* a_d    = (float*)w;  w += align_up((size_t)N * NHEAD * 4);
    int*   deg    = (int*)w;    w += align_up((size_t)N * 4);
    int*   rowptr = (int*)w;    w += align_up((size_t)(N + 1) * 4);
    int*   cursor = (int*)w;    w += align_up((size_t)N * 4);
    int*   csrsrc = (int*)w;    w += align_up((size_t)E * 4);
    int*   bsum   = (int*)w;    w += align_up(((size_t)N / 1024 + 2) * 4);
    __half* Wf1   = (__half*)w; w += align_up((size_t)128 * 256 * 2);
    __half* Wf2   = (__half*)w; w += align_up((size_t)32 * 128 * 2);
    __half* Wf3   = (__half*)w; w += align_up((size_t)32 * 256 * 2);   // K zero-padded to 32

    const int EB = 256;
    const int eg = (E + EB - 1) / EB;
    const int pgrid = (N + 63) / 64;        // 64 nodes per block (16/wave)
    const int ngrid = (N + 3) / 4;          // 4 dst-waves per 256-thread block
    const int NB = (N + 1023) / 1024;       // scan chunks

    // ---- W fragment swizzle + CSR build (reused by all 3 layers) ----
    prep_all<<<22, 256, 0, stream>>>(W1, W2, W3, Wf1, Wf2, Wf3);
    (void)hipMemsetAsync(deg, 0, (size_t)N * 4, stream);
    hist_kernel<<<eg, EB, 0, stream>>>(ei, E, deg);
    blocksum_kernel<<<NB, 256, 0, stream>>>(deg, N, bsum);
    bscan_kernel<<<1, 64, 0, stream>>>(bsum, NB);
    rowptr_kernel<<<NB, 256, 0, stream>>>(deg, bsum, N, E, rowptr, cursor);
    scatter_kernel<<<eg, EB, 0, stream>>>(ei, E, cursor, csrsrc);

    // ---------------- Layer 1: din=128, C=32, HC=256 ----------------
    proj_mfma<128, 256, 32><<<pgrid, 256, 0, stream>>>(
        x, 128, 0, Wf1, as1, ad1, xp, a_s, a_d, N);
    aggr_kernel<32><<<ngrid, 256, 0, stream>>>(rowptr, csrsrc, a_s, a_d, xp, b1, out, 0, N);

    // ---------------- Layer 2: din=32, C=16, HC=128 (input = out[:,0:32]) ----------------
    proj_mfma<32, 128, 16><<<pgrid, 256, 0, stream>>>(
        out, OUT_COLS, 0, Wf2, as2, ad2, xp, a_s, a_d, N);
    aggr_kernel<16><<<ngrid, 256, 0, stream>>>(rowptr, csrsrc, a_s, a_d, xp, b2, out, 32, N);

    // ---------------- Layer 3: din=16, C=32, HC=256 (input = out[:,32:48]) ----------------
    proj_mfma<16, 256, 32><<<pgrid, 256, 0, stream>>>(
        out, OUT_COLS, 32, Wf3, as3, ad3, xp, a_s, a_d, N);
    aggr_kernel<32><<<ngrid, 256, 0, stream>>>(rowptr, csrsrc, a_s, a_d, xp, b3, out, 48, N);
}

// Round 13
// 212.091 us; speedup vs baseline: 4.3050x; 1.0085x over previous
//
#include <hip/hip_runtime.h>
#include <hip/hip_fp16.h>
#include <math.h>

#define NHEAD 8
#define NEG_SLOPE 0.2f
#define OUT_COLS 80

typedef _Float16 f16x8 __attribute__((ext_vector_type(8)));
typedef float f32x4 __attribute__((ext_vector_type(4)));

__device__ __forceinline__ float lrelu(float x) {
    return x > 0.f ? x : NEG_SLOPE * x;
}

// ---------------- W fragment pre-swizzle + deg zero-fill ----------------
// B-frag layout for mfma_f32_16x16x32_f16:
//   elems 0-3: k = kc*32 + (lane>>4)*4 + j,      col = nt*16 + (lane&15)
//   elems 4-7: k = kc*32 + 16 + (lane>>4)*4 + (j-4)
// Wf[(kc*NT+nt)*64 + lane][8] as halves -> one coalesced float4 per lane.
// k >= DINLIM reads as 0 (K zero-padding for DIN=16 layers).
__device__ __forceinline__ void prep32_frag(const float* __restrict__ W,
                                            __half* __restrict__ Wf,
                                            int HC, int NT, int t, int DINLIM) {
    const int lane = t & 63, f = t >> 6;
    const int kc = f / NT, nt = f % NT;
    const int col = nt * 16 + (lane & 15);
    const int kb = kc * 32 + ((lane >> 4) << 2);
    __half v[8];
#pragma unroll
    for (int j = 0; j < 8; ++j) {
        const int k = kb + (j & 3) + ((j >> 2) << 4);
        v[j] = (k < DINLIM) ? __float2half(W[k * HC + col]) : __half(0.f);
    }
    *(float4*)(Wf + (size_t)t * 8) = *(float4*)&v[0];
}

// blocks 0-15: L1 frags; 16-17: L2; 18-21: L3; 22+: zero deg (int4 stores).
__global__ __launch_bounds__(256) void prep_all(
    const float* __restrict__ W1, const float* __restrict__ W2,
    const float* __restrict__ W3,
    __half* __restrict__ Wf1, __half* __restrict__ Wf2, __half* __restrict__ Wf3,
    int* __restrict__ deg, int N) {
    const int b = blockIdx.x, tid = threadIdx.x;
    if (b < 16) {                       // L1: 4 kc x 16 nt x 64 = 4096 frag-threads
        prep32_frag(W1, Wf1, 256, 16, b * 256 + tid, 128);
    } else if (b < 18) {                // L2: 1 kc x 8 nt x 64 = 512
        const int t = (b - 16) * 256 + tid;
        if (t < 512) prep32_frag(W2, Wf2, 128, 8, t, 32);
    } else if (b < 22) {                // L3: 1 kc x 16 nt x 64 = 1024 (K zero-padded)
        const int t = (b - 18) * 256 + tid;
        if (t < 1024) prep32_frag(W3, Wf3, 256, 16, t, 16);
    } else {                            // zero deg
        const int i = ((b - 22) * 256 + tid) * 4;
        if (i + 3 < N) {
            *(int4*)(deg + i) = make_int4(0, 0, 0, 0);
        } else {
#pragma unroll
            for (int q = 0; q < 4; ++q) if (i + q < N) deg[i + q] = 0;
        }
    }
}

// ---------------- projection via MFMA ----------------
// Block = 4 waves; wave = 16 nodes x all HC cols, K via 16x16x32 (zero-padded for DIN=16).
// Epilogue: LDS transpose (row stride HC+8 halves keeps float4 16B-aligned),
// coalesced fp16 xp writeout fused with a_s/a_d dots.
template<int DIN, int HC, int C>
__global__ __launch_bounds__(256) void proj_mfma(
    const float* __restrict__ xin, int xstride, int xoff,
    const __half* __restrict__ Wf,
    const float* __restrict__ as_flat, const float* __restrict__ ad_flat,
    __half* __restrict__ xp, float* __restrict__ a_s, float* __restrict__ a_d,
    int n_nodes) {
    constexpr int NT = HC / 16;
    __shared__ __half lds[4][16][HC + 8];
    const int lane = threadIdx.x & 63;
    const int wv = threadIdx.x >> 6;
    const int n0 = (blockIdx.x * 4 + wv) * 16;
    const int nlast = n_nodes - 1;
    const int ar = min(n0 + (lane & 15), nlast);
    const int kb = (lane >> 4) << 2;
    const float* __restrict__ xr = xin + (size_t)ar * xstride + xoff;

    f32x4 acc[NT];
#pragma unroll
    for (int nt = 0; nt < NT; ++nt) acc[nt] = (f32x4){0.f, 0.f, 0.f, 0.f};

    if constexpr (DIN >= 32) {
        constexpr int KCNT = DIN / 32;
#pragma unroll
        for (int kc = 0; kc < KCNT; ++kc) {
            const float4 xv0 = *(const float4*)(xr + kc * 32 + kb);
            const float4 xv1 = *(const float4*)(xr + kc * 32 + 16 + kb);
            f16x8 af;
            af[0] = (_Float16)xv0.x; af[1] = (_Float16)xv0.y;
            af[2] = (_Float16)xv0.z; af[3] = (_Float16)xv0.w;
            af[4] = (_Float16)xv1.x; af[5] = (_Float16)xv1.y;
            af[6] = (_Float16)xv1.z; af[7] = (_Float16)xv1.w;
            const __half* __restrict__ Wb = Wf + ((size_t)kc * NT * 64 + lane) * 8;
#pragma unroll
            for (int nt = 0; nt < NT; ++nt) {
                const f16x8 bf = *(const f16x8*)(Wb + (size_t)nt * 64 * 8);
                acc[nt] = __builtin_amdgcn_mfma_f32_16x16x32_f16(af, bf, acc[nt], 0, 0, 0);
            }
        }
    } else {
        // DIN=16: K zero-padded to 32 (Wf elems for k>=16 are 0)
        const float4 xv0 = *(const float4*)(xr + kb);
        f16x8 af;
        af[0] = (_Float16)xv0.x; af[1] = (_Float16)xv0.y;
        af[2] = (_Float16)xv0.z; af[3] = (_Float16)xv0.w;
        af[4] = (_Float16)0.f; af[5] = (_Float16)0.f;
        af[6] = (_Float16)0.f; af[7] = (_Float16)0.f;
        const __half* __restrict__ Wb = Wf + (size_t)lane * 8;
#pragma unroll
        for (int nt = 0; nt < NT; ++nt) {
            const f16x8 bf = *(const f16x8*)(Wb + (size_t)nt * 64 * 8);
            acc[nt] = __builtin_amdgcn_mfma_f32_16x16x32_f16(af, bf, acc[nt], 0, 0, 0);
        }
    }

    // C-frag -> LDS (col = lane&15 within nt, rows kb..kb+3)
#pragma unroll
    for (int nt = 0; nt < NT; ++nt) {
#pragma unroll
        for (int r = 0; r < 4; ++r)
            lds[wv][kb + r][nt * 16 + (lane & 15)] = __float2half(acc[nt][r]);
    }

    // coalesced writeout + attention dots
    constexpr int F4PR = HC / 8;            // float4 chunks per row
    constexpr int ITER = 16 * F4PR / 64;
    constexpr int LPH = C / 8;              // lanes per (row, head)
#pragma unroll
    for (int i = 0; i < ITER; ++i) {
        const int flat = i * 64 + lane;
        const int row = flat / F4PR;
        const int co = (flat % F4PR) * 8;
        const int node = n0 + row;
        __half hv[8];
        *(float4*)hv = *(const float4*)&lds[wv][row][co];
        const float4 as0 = *(const float4*)(as_flat + co);
        const float4 as1 = *(const float4*)(as_flat + co + 4);
        const float4 ad0 = *(const float4*)(ad_flat + co);
        const float4 ad1 = *(const float4*)(ad_flat + co + 4);
        float xv[8];
#pragma unroll
        for (int j = 0; j < 8; ++j) xv[j] = __half2float(hv[j]);
        float ps = xv[0] * as0.x + xv[1] * as0.y + xv[2] * as0.z + xv[3] * as0.w
                 + xv[4] * as1.x + xv[5] * as1.y + xv[6] * as1.z + xv[7] * as1.w;
        float pd = xv[0] * ad0.x + xv[1] * ad0.y + xv[2] * ad0.z + xv[3] * ad0.w
                 + xv[4] * ad1.x + xv[5] * ad1.y + xv[6] * ad1.z + xv[7] * ad1.w;
#pragma unroll
        for (int off = 1; off < LPH; off <<= 1) {
            ps += __shfl_xor(ps, off, 64);
            pd += __shfl_xor(pd, off, 64);
        }
        if (node <= nlast) {
            *(float4*)(xp + (size_t)node * HC + co) = *(float4*)hv;
            if ((flat & (LPH - 1)) == 0) {
                const int h = co / C;
                a_s[(size_t)node * NHEAD + h] = ps;
                a_d[(size_t)node * NHEAD + h] = pd;
            }
        }
    }
}

// ---------------- CSR build ----------------
__global__ void hist_kernel(const int* __restrict__ ei, int E, int* __restrict__ deg) {
    const int e = blockIdx.x * blockDim.x + threadIdx.x;
    if (e < E) atomicAdd(&deg[ei[E + e]], 1);
}

__global__ __launch_bounds__(256) void blocksum_kernel(const int* __restrict__ deg, int N,
                                                       int* __restrict__ bsum) {
    __shared__ int red[256];
    const int t = threadIdx.x;
    const int base = blockIdx.x * 1024 + t * 4;
    int s = 0;
    if (base + 3 < N) {
        const int4 v = *(const int4*)(deg + base);
        s = v.x + v.y + v.z + v.w;
    } else {
#pragma unroll
        for (int i = 0; i < 4; ++i) if (base + i < N) s += deg[base + i];
    }
    red[t] = s;
    __syncthreads();
    for (int off = 128; off > 0; off >>= 1) {
        if (t < off) red[t] += red[t + off];
        __syncthreads();
    }
    if (t == 0) bsum[blockIdx.x] = red[0];
}

__global__ __launch_bounds__(64) void bscan_kernel(int* __restrict__ bsum, int NB) {
    const int lane = threadIdx.x;
    int run = 0;
    for (int base = 0; base < NB; base += 64) {
        const int i = base + lane;
        const int v = (i < NB) ? bsum[i] : 0;
        int inc = v;
#pragma unroll
        for (int off = 1; off < 64; off <<= 1) {
            const int u = __shfl_up(inc, off, 64);
            if (lane >= off) inc += u;
        }
        if (i < NB) bsum[i] = run + inc - v;
        run += __shfl(inc, 63, 64);
    }
}

__global__ __launch_bounds__(256) void rowptr_kernel(const int* __restrict__ deg,
                                                     const int* __restrict__ bsum,
                                                     int N, int E,
                                                     int* __restrict__ rowptr,
                                                     int* __restrict__ cursor) {
    __shared__ int tsum[256];
    const int t = threadIdx.x;
    const int base = blockIdx.x * 1024 + t * 4;
    int v[4];
    int s = 0;
#pragma unroll
    for (int i = 0; i < 4; ++i) {
        v[i] = (base + i < N) ? deg[base + i] : 0;
        s += v[i];
    }
    tsum[t] = s;
    __syncthreads();
    for (int off = 1; off < 256; off <<= 1) {
        const int u = (t >= off) ? tsum[t - off] : 0;
        __syncthreads();
        tsum[t] += u;
        __syncthreads();
    }
    int run = bsum[blockIdx.x] + tsum[t] - s;
#pragma unroll
    for (int i = 0; i < 4; ++i) {
        if (base + i < N) {
            rowptr[base + i] = run;
            cursor[base + i] = run;
            run += v[i];
        }
    }
    if (blockIdx.x == 0 && t == 0) rowptr[N] = E;
}

__global__ void scatter_kernel(const int* __restrict__ ei, int E,
                               int* __restrict__ cursor, int* __restrict__ csr_src) {
    const int e = blockIdx.x * blockDim.x + threadIdx.x;
    if (e < E) {
        const int pos = atomicAdd(&cursor[ei[E + e]], 1);
        csr_src[pos] = ei[e];
    }
}

// ---------------- fused softmax+aggregation: one wave per dst ----------------
// Phase A: lane=(slot,head) computes unnormalized ex (fast __expf).
// Phase B: unconditional gather rounds; packed fp16 FMA accumulators;
// 32-bit (u24-friendly) gather addressing.
template<int C>
__global__ __launch_bounds__(256) void aggr_kernel(
    const int* __restrict__ rowptr, const int* __restrict__ csr_src,
    const float* __restrict__ a_s, const float* __restrict__ a_d,
    const __half* __restrict__ xp, const float* __restrict__ bias,
    float* __restrict__ out, int out_off, int N) {
    constexpr int HC = NHEAD * C;
    constexpr int LPE = HC / 8;     // lanes per edge-row (32 or 16)
    constexpr int EPW = 64 / LPE;   // edges in flight per wave (2 or 4)
    constexpr int CQ = C / 8;       // c-octs per head (4 or 2)
    const int n = (blockIdx.x * blockDim.x + threadIdx.x) >> 6;
    if (n >= N) return;
    const int lane = threadIdx.x & 63;
    const int iA = lane >> 3, hA = lane & 7;        // phase-A role
    const int le = lane & (LPE - 1);                // phase-B role
    const int epar = lane / LPE;
    const int h = le / CQ;
    const int c0 = (le % CQ) * 8;
    const int row0 = rowptr[n];
    const int deg = rowptr[n + 1] - row0;
    const int items = deg + 1;                      // + self-loop

    const float adhA = a_d[(size_t)n * NHEAD + hA];
    float sacc = 0.f;
    __half2 acch[4];
#pragma unroll
    for (int j = 0; j < 4; ++j) acch[j] = __float2half2_rn(0.f);

    const unsigned lelem = h * C + c0;              // lane's element offset in a row

    for (int base = 0; base < items; base += 8) {
        const int idx = base + iA;
        int src = n;
        float ex = 0.f;
        if (idx < items) {
            if (idx < deg) src = csr_src[row0 + idx];
            ex = __expf(lrelu(a_s[(size_t)src * NHEAD + hA] + adhA));
        }
        sacc += ex;
#pragma unroll
        for (int g = 0; g < 8; g += EPW) {
            const int it = g + epar;
            const unsigned srcb = (unsigned)__shfl(src, it * 8, 64);
            const float exb = __shfl(ex, it * 8 + h, 64);
            const __half2 exh = __float2half2_rn(exb);
            const float4 r = *(const float4*)(xp + srcb * (unsigned)HC + lelem);
            const __half2* h2 = (const __half2*)&r;
#pragma unroll
            for (int q = 0; q < 4; ++q)
                acch[q] = __hfma2(exh, h2[q], acch[q]);
        }
    }
    // softmax denominators: reduce over slots -> lane L holds s for head L&7
    sacc += __shfl_xor(sacc, 8, 64);
    sacc += __shfl_xor(sacc, 16, 64);
    sacc += __shfl_xor(sacc, 32, 64);
    const float sinv = 1.f / __shfl(sacc, h, 64);

    // widen packed accumulators to fp32 for the cross-lane reductions
    float acc[8];
#pragma unroll
    for (int q = 0; q < 4; ++q) {
        const float2 f = __half22float2(acch[q]);
        acc[2 * q] = f.x;
        acc[2 * q + 1] = f.y;
    }

    // combine edge-parallel copies (same (h,c-oct), different edge subsets)
#pragma unroll
    for (int off = LPE; off < 64; off <<= 1) {
#pragma unroll
        for (int j = 0; j < 8; ++j) acc[j] += __shfl_xor(acc[j], off, 64);
    }
#pragma unroll
    for (int j = 0; j < 8; ++j) acc[j] *= sinv;      // per-head normalize
    // head-mean reduce (over h lanes)
#pragma unroll
    for (int off = CQ; off < LPE; off <<= 1) {
#pragma unroll
        for (int j = 0; j < 8; ++j) acc[j] += __shfl_xor(acc[j], off, 64);
    }
    if (lane < CQ) {
        float v[8];
#pragma unroll
        for (int j = 0; j < 8; ++j)
            v[j] = fmaxf(acc[j] * (1.f / NHEAD) + bias[lane * 8 + j], 0.f);
        float* op = out + (size_t)n * OUT_COLS + out_off + lane * 8;
        *(float4*)op = make_float4(v[0], v[1], v[2], v[3]);
        *(float4*)(op + 4) = make_float4(v[4], v[5], v[6], v[7]);
    }
}

static inline size_t align_up(size_t x) { return (x + 255) & ~size_t(255); }

extern "C" void kernel_launch(void* const* d_in, const int* in_sizes, int n_in,
                              void* d_out, int out_size, void* d_ws, size_t ws_size,
                              hipStream_t stream) {
    const float* x  = (const float*)d_in[0];
    const int*   ei = (const int*)d_in[1];
    const float* W1  = (const float*)d_in[2];
    const float* as1 = (const float*)d_in[3];
    const float* ad1 = (const float*)d_in[4];
    const float* b1  = (const float*)d_in[5];
    const float* W2  = (const float*)d_in[6];
    const float* as2 = (const float*)d_in[7];
    const float* ad2 = (const float*)d_in[8];
    const float* b2  = (const float*)d_in[9];
    const float* W3  = (const float*)d_in[10];
    const float* as3 = (const float*)d_in[11];
    const float* ad3 = (const float*)d_in[12];
    const float* b3  = (const float*)d_in[13];
    float* out = (float*)d_out;

    const int N = in_sizes[0] / 128;
    const int E = in_sizes[1] / 2;

    // workspace layout
    char* w = (char*)d_ws;
    __half* xp    = (__half*)w; w += align_up((size_t)N * 256 * 2);
    float* a_s    = (float*)w;  w += align_up((size_t)N * NHEAD * 4);
    float* a_d    = (float*)w;  w += align_up((size_t)N * NHEAD * 4);
    int*   deg    = (int*)w;    w += align_up((size_t)N * 4);
    int*   rowptr = (int*)w;    w += align_up((size_t)(N + 1) * 4);
    int*   cursor = (int*)w;    w += align_up((size_t)N * 4);
    int*   csrsrc = (int*)w;    w += align_up((size_t)E * 4);
    int*   bsum   = (int*)w;    w += align_up(((size_t)N / 1024 + 2) * 4);
    __half* Wf1   = (__half*)w; w += align_up((size_t)128 * 256 * 2);
    __half* Wf2   = (__half*)w; w += align_up((size_t)32 * 128 * 2);
    __half* Wf3   = (__half*)w; w += align_up((size_t)32 * 256 * 2);   // K zero-padded to 32

    const int EB = 256;
    const int eg = (E + EB - 1) / EB;
    const int pgrid = (N + 63) / 64;        // 64 nodes per block (16/wave)
    const int ngrid = (N + 3) / 4;          // 4 dst-waves per 256-thread block
    const int NB = (N + 1023) / 1024;       // scan chunks
    const int zblocks = (N + 1023) / 1024;  // deg-zero blocks (256 thr x int4)

    // ---- W fragment swizzle + deg zero + CSR build (reused by all 3 layers) ----
    prep_all<<<22 + zblocks, 256, 0, stream>>>(W1, W2, W3, Wf1, Wf2, Wf3, deg, N);
    hist_kernel<<<eg, EB, 0, stream>>>(ei, E, deg);
    blocksum_kernel<<<NB, 256, 0, stream>>>(deg, N, bsum);
    bscan_kernel<<<1, 64, 0, stream>>>(bsum, NB);
    rowptr_kernel<<<NB, 256, 0, stream>>>(deg, bsum, N, E, rowptr, cursor);
    scatter_kernel<<<eg, EB, 0, stream>>>(ei, E, cursor, csrsrc);

    // ---------------- Layer 1: din=128, C=32, HC=256 ----------------
    proj_mfma<128, 256, 32><<<pgrid, 256, 0, stream>>>(
        x, 128, 0, Wf1, as1, ad1, xp, a_s, a_d, N);
    aggr_kernel<32><<<ngrid, 256, 0, stream>>>(rowptr, csrsrc, a_s, a_d, xp, b1, out, 0, N);

    // ---------------- Layer 2: din=32, C=16, HC=128 (input = out[:,0:32]) ----------------
    proj_mfma<32, 128, 16><<<pgrid, 256, 0, stream>>>(
        out, OUT_COLS, 0, Wf2, as2, ad2, xp, a_s, a_d, N);
    aggr_kernel<16><<<ngrid, 256, 0, stream>>>(rowptr, csrsrc, a_s, a_d, xp, b2, out, 32, N);

    // ---------------- Layer 3: din=16, C=32, HC=256 (input = out[:,32:48]) ----------------
    proj_mfma<16, 256, 32><<<pgrid, 256, 0, stream>>>(
        out, OUT_COLS, 32, Wf3, as3, ad3, xp, a_s, a_d, N);
    aggr_kernel<32><<<ngrid, 256, 0, stream>>>(rowptr, csrsrc, a_s, a_d, xp, b3, out, 48, N);
}